// Round 6
// baseline (97.752 us; speedup 1.0000x reference)
//
#include <hip/hip_runtime.h>

// Concordance index, status-partitioned formulation (validated R4/R5, absmax 0.0).
// answer = (CC_full - K) / (TP_full - K), K = #(status==1), le == !ge.
//   region (1,1): cc = (ge==geh), tp = 1      -> tp analytic K^2
//   region (0,1) == (1,0) transposed          -> compute once, double
//   region (0,0): contributes nothing         -> skipped
// EQ = Sum_{i,j in st1} (ge==geh) computed as IAp*Jp - NE where NE counts
// (ge!=geh) over padded tiles: sentinels are built so ne==1 for ANY pair
// involving a sentinel (j-pad staged as (+inf,-inf); region-A i-pad
// (-inf,+inf)), so they're absorbed by the IAp*Jp constant. Region-B pads
// give ge=0 -> contribute 0 to BG/BC.
// CC_full = EQ + 2*BC ; TP_full = K^2 + 2*BG.
// 3 graph nodes: 64B memset, compact, pairs(+last-block finalize).
// R3 lesson kept: compile-time trip counts, uniform flow, LDS broadcast.

#define BLOCK 256
#define TJ 256
#define IT 4
#define TI (BLOCK * IT)          // 1024
#define GRID_PAIRS 1024

// ws: [0] u32 cnts[2] (K,M); [8] ull acc[3] (NE,BC,BG); [32] u32 done; [64] float2 p1[stride], p0[stride]

__global__ __launch_bounds__(256) void compact_kernel(
    const float* __restrict__ y, const float* __restrict__ yh,
    const int* __restrict__ status, int n,
    unsigned* __restrict__ cnts,
    float2* __restrict__ p1, float2* __restrict__ p0)
{
    int i = blockIdx.x * 256 + threadIdx.x;
    int lane = threadIdx.x & 63;
    bool act = i < n;
    float yv  = act ? y[i]  : 0.0f;
    float yhv = act ? yh[i] : 0.0f;
    bool st = act && (status[i] == 1);
    unsigned long long m1 = __ballot(st);
    unsigned long long m0 = __ballot(act && !st);
    unsigned long long lt = (1ull << lane) - 1ull;
    unsigned b1 = 0, b0 = 0;
    if (lane == 0) {
        b1 = atomicAdd(&cnts[0], (unsigned)__popcll(m1));
        b0 = atomicAdd(&cnts[1], (unsigned)__popcll(m0));
    }
    b1 = __shfl(b1, 0, 64);
    b0 = __shfl(b0, 0, 64);
    if (st) {
        p1[b1 + (unsigned)__popcll(m1 & lt)] = make_float2(yv, yhv);
    } else if (act) {
        p0[b0 + (unsigned)__popcll(m0 & lt)] = make_float2(yv, yhv);
    }
}

__global__ __launch_bounds__(BLOCK) void pairs_kernel(
    const unsigned* __restrict__ cnts,
    const float2* __restrict__ p1, const float2* __restrict__ p0,
    unsigned long long* __restrict__ acc, unsigned* __restrict__ done,
    float* __restrict__ out)
{
    __shared__ float2 s_j[TJ];
    const int tid = threadIdx.x;
    const unsigned K = cnts[0], M = cnts[1];
    const int ntJ  = (int)((K + TJ - 1) / TJ);
    const int ntIA = (int)((K + TI - 1) / TI);
    const int ntIB = (int)((M + TI - 1) / TI);
    const int ntA  = ntIA * ntJ;
    const int ntot = ntA + ntIB * ntJ;
    const float PINF = __int_as_float(0x7f800000);
    const float NINF = __int_as_float(0xff800000);

    unsigned accNE = 0, accBC = 0, accBG = 0;

    for (int t = blockIdx.x; t < ntot; t += gridDim.x) {
        bool isA = t < ntA;
        int tt = isA ? t : t - ntA;
        int ti = tt / ntJ;
        int tj = tt - ti * ntJ;

        // stage j chunk (st1 set); edge slots -> sentinel (outside hot loop)
        {
            int jidx = tj * TJ + tid;                 // < K+255 < stride: safe
            float2 jv = p1[jidx];
            if ((unsigned)jidx >= K) jv = make_float2(PINF, NINF);
            s_j[tid] = jv;
        }
        __syncthreads();

        const float2* pi = isA ? p1 : p0;
        unsigned ilim = isA ? K : M;
        float2 v0, v1, v2, v3;
        {
            int ib = ti * TI + tid;                   // < ilim+1023 < stride: safe
            float2 sA = make_float2(NINF, PINF);      // region A i-pad: ne=1 always
            float2 sB = make_float2(NINF, NINF);      // region B i-pad: ge=0 always
            float2 sent = isA ? sA : sB;
            v0 = pi[ib];              if ((unsigned)(ib)             >= ilim) v0 = sent;
            v1 = pi[ib + BLOCK];      if ((unsigned)(ib + BLOCK)     >= ilim) v1 = sent;
            v2 = pi[ib + 2 * BLOCK];  if ((unsigned)(ib + 2 * BLOCK) >= ilim) v2 = sent;
            v3 = pi[ib + 3 * BLOCK];  if ((unsigned)(ib + 3 * BLOCK) >= ilim) v3 = sent;
        }

        if (isA) {
            unsigned n0 = 0, n1 = 0;
#pragma unroll 8
            for (int jj = 0; jj < TJ; ++jj) {
                float2 p = s_j[jj];
                n0 += (unsigned)((v0.x >= p.x) != (v0.y >= p.y));
                n1 += (unsigned)((v1.x >= p.x) != (v1.y >= p.y));
                n0 += (unsigned)((v2.x >= p.x) != (v2.y >= p.y));
                n1 += (unsigned)((v3.x >= p.x) != (v3.y >= p.y));
            }
            accNE += n0 + n1;
        } else {
            unsigned g0 = 0, g1 = 0, c0 = 0, c1 = 0;
#pragma unroll 8
            for (int jj = 0; jj < TJ; ++jj) {
                float2 p = s_j[jj];
                bool a0 = v0.x >= p.x, b0 = v0.y >= p.y;
                bool a1 = v1.x >= p.x, b1 = v1.y >= p.y;
                bool a2 = v2.x >= p.x, b2 = v2.y >= p.y;
                bool a3 = v3.x >= p.x, b3 = v3.y >= p.y;
                g0 += (unsigned)a0; c0 += (unsigned)(a0 & b0);
                g1 += (unsigned)a1; c1 += (unsigned)(a1 & b1);
                g0 += (unsigned)a2; c0 += (unsigned)(a2 & b2);
                g1 += (unsigned)a3; c1 += (unsigned)(a3 & b3);
            }
            accBG += g0 + g1; accBC += c0 + c1;
        }
        __syncthreads();
    }

    // wave shuffle -> LDS -> 3 atomics per block -> last-block finalize
#pragma unroll
    for (int off = 32; off > 0; off >>= 1) {
        accNE += __shfl_down(accNE, off, 64);
        accBC += __shfl_down(accBC, off, 64);
        accBG += __shfl_down(accBG, off, 64);
    }
    __shared__ unsigned rN[4], rC[4], rG[4];
    int wav = tid >> 6, lane = tid & 63;
    if (lane == 0) { rN[wav] = accNE; rC[wav] = accBC; rG[wav] = accBG; }
    __syncthreads();
    if (tid == 0) {
        unsigned long long ne = (unsigned long long)rN[0] + rN[1] + rN[2] + rN[3];
        unsigned long long bc = (unsigned long long)rC[0] + rC[1] + rC[2] + rC[3];
        unsigned long long bg = (unsigned long long)rG[0] + rG[1] + rG[2] + rG[3];
        if (ne) atomicAdd(&acc[0], ne);
        if (bc) atomicAdd(&acc[1], bc);
        if (bg) atomicAdd(&acc[2], bg);
        __threadfence();
        if (atomicAdd(done, 1u) == (unsigned)(gridDim.x - 1)) {
            __threadfence();
            unsigned long long NE = atomicAdd(&acc[0], 0ull);
            unsigned long long BC = atomicAdd(&acc[1], 0ull);
            unsigned long long BG = atomicAdd(&acc[2], 0ull);
            unsigned long long Kl = K;
            unsigned long long slots = (unsigned long long)(ntIA * TI) *
                                       (unsigned long long)(ntJ * TJ);
            unsigned long long EQ = slots - NE;
            unsigned long long CC = EQ + 2ull * BC;
            unsigned long long TP = Kl * Kl + 2ull * BG;
            long long cn = (long long)CC - (long long)Kl;
            long long tn = (long long)TP - (long long)Kl;
            out[0] = (float)cn / (float)tn;
        }
    }
}

extern "C" void kernel_launch(void* const* d_in, const int* in_sizes, int n_in,
                              void* d_out, int out_size, void* d_ws, size_t ws_size,
                              hipStream_t stream) {
    const float* y      = (const float*)d_in[0];
    const float* y_hat  = (const float*)d_in[1];
    const int*   status = (const int*)d_in[2];
    float* out = (float*)d_out;
    int n = in_sizes[0];
    int stride = n + 1024;

    char* base = (char*)d_ws;
    unsigned* cnts = (unsigned*)base;
    unsigned long long* acc = (unsigned long long*)(base + 8);
    unsigned* done = (unsigned*)(base + 32);
    float2* p1 = (float2*)(base + 64);
    float2* p0 = p1 + stride;

    hipMemsetAsync(base, 0, 64, stream);

    hipLaunchKernelGGL(compact_kernel, dim3((n + 255) / 256), dim3(256), 0, stream,
                       y, y_hat, status, n, cnts, p1, p0);

    hipLaunchKernelGGL(pairs_kernel, dim3(GRID_PAIRS), dim3(BLOCK), 0, stream,
                       cnts, p1, p0, acc, done, out);
}